// Round 14
// baseline (5024.252 us; speedup 1.0000x reference)
//
#include <hip/hip_runtime.h>
#include <hip/hip_bf16.h>
#include <stdint.h>

// RNN: h_t = relu(xs_t @ W_ih^T + h_{t-1} @ W_hh^T); ys = (h_seq @ W_out^T) -> [B,T,O]
// R14: per-CU load-volume attack. Diagnosis: every protocol R5-R13 moved 128KB/CU/step of
// bypass loads; measured 6.65us/step = 128KB @ 8B/cy/CU (the per-CU vmem service rate).
// New geometry: 256 blocks = 8 chains (8 b-rows) x 32 j-blocks (J=64). W_hh fully in
// registers (128 VGPR/lane). h_{t-1} (32KB) staged ONCE into swizzled LDS per block
// (64B/thread, tag-validated bypass loads), A-frags via ds_read_b128. Per-CU global
// loads: 128KB -> 32KB per step. Protocol/layout: R12's tag+flag-hint (no drain),
// R11's sl_idx8 slices, R12's lossless |P| + sign-plane.

#define TT 512
#define BB 64
#define NIN 1024
#define NH 2048
#define NOUT 1024

typedef __attribute__((ext_vector_type(8))) short bf8;
typedef __attribute__((ext_vector_type(4))) float f4;
typedef __attribute__((ext_vector_type(4))) unsigned int u4;

static __device__ __forceinline__ unsigned short f2bf(float f) {
  __hip_bfloat16 h = __float2bfloat16(f);
  return __builtin_bit_cast(unsigned short, h);
}
static __device__ __forceinline__ float bf2f(unsigned short v) {
  return __bfloat162float(__builtin_bit_cast(__hip_bfloat16, v));
}
static __device__ __forceinline__ u4 pack8(const float* f) {
  u4 r;
#pragma unroll
  for (int i = 0; i < 4; ++i) {
    unsigned lo = f2bf(f[2 * i]);
    unsigned hi = f2bf(f[2 * i + 1]);
    r[i] = lo | (hi << 16);
  }
  return r;
}

// slice layout: (m = t*64+b, col) -> [t][g=b>>3][jb=col>>6][r=b&7][jl=col&63]
static __device__ __forceinline__ size_t sl_idx8(int m, int col) {
  return ((((size_t)(m >> 6) * 8 + ((m & 63) >> 3)) * 32 + (col >> 6)) << 9) +
         (size_t)((m & 63) & 7) * 64 + (col & 63);
}

// ---------------- generic C[M,N] = A[M,K] * B[N,K]^T (bf16 MFMA) ----------------
// <false,false>: phase 1 — store |P| (signs cleared) + sign bits into plane (1b/elem).
// <true,true>:   phase 3 — A = tagged h (strip signs), store f32 out[b][t][n].
template <bool ABF, bool TRANS>
__global__ void gemm_bt(const void* __restrict__ Av, const float* __restrict__ Bw,
                        void* __restrict__ Cv, unsigned char* __restrict__ plane,
                        int M, int N, int K) {
  constexpr int BM = 128, BN = 128, BK = 32;
  __shared__ u4 As[BM * 4];
  __shared__ u4 Bs[BN * 4];
  const int nt = N / BN;
  const int mi = (int)blockIdx.x / nt;
  const int ni = (int)blockIdx.x % nt;
  const int m0 = mi * BM, n0 = ni * BN;
  const int t = threadIdx.x;
  const int l = t & 63, w = t >> 6, wr = w >> 1, wc = w & 1;
  const int lr = l & 15, lq = l >> 4;

  f4 acc[4][4] = {};

  const int srow = t >> 1;
  const int sc0 = (t & 1) * 2;
  const u4 msk = {0x7fff7fffu, 0x7fff7fffu, 0x7fff7fffu, 0x7fff7fffu};

  for (int kt = 0; kt < K; kt += BK) {
    if (ABF) {
      const unsigned short* A = (const unsigned short*)Av;
#pragma unroll
      for (int cc = 0; cc < 2; ++cc) {
        int c = sc0 + cc;
        u4 v = *(const u4*)(A + sl_idx8(m0 + srow, kt + c * 8));
        v &= msk;  // strip h tag signs
        As[srow * 4 + (c ^ ((srow ^ (srow >> 2)) & 3))] = v;
      }
    } else {
      const float* A = (const float*)Av;
#pragma unroll
      for (int cc = 0; cc < 2; ++cc) {
        int c = sc0 + cc;
        const float* p = A + (size_t)(m0 + srow) * K + kt + c * 8;
        float4 v0 = *(const float4*)p;
        float4 v1 = *(const float4*)(p + 4);
        float f[8] = {v0.x, v0.y, v0.z, v0.w, v1.x, v1.y, v1.z, v1.w};
        As[srow * 4 + (c ^ ((srow ^ (srow >> 2)) & 3))] = pack8(f);
      }
    }
#pragma unroll
    for (int cc = 0; cc < 2; ++cc) {
      int c = sc0 + cc;
      const float* p = Bw + (size_t)(n0 + srow) * K + kt + c * 8;
      float4 v0 = *(const float4*)p;
      float4 v1 = *(const float4*)(p + 4);
      float f[8] = {v0.x, v0.y, v0.z, v0.w, v1.x, v1.y, v1.z, v1.w};
      Bs[srow * 4 + (c ^ ((srow ^ (srow >> 2)) & 3))] = pack8(f);
    }
    __syncthreads();

    bf8 a[4], b[4];
#pragma unroll
    for (int i = 0; i < 4; ++i) {
      int ra = wr * 64 + i * 16 + lr;
      a[i] = __builtin_bit_cast(bf8, As[ra * 4 + (lq ^ ((ra ^ (ra >> 2)) & 3))]);
      int rb = wc * 64 + i * 16 + lr;
      b[i] = __builtin_bit_cast(bf8, Bs[rb * 4 + (lq ^ ((rb ^ (rb >> 2)) & 3))]);
    }
#pragma unroll
    for (int i = 0; i < 4; ++i)
#pragma unroll
      for (int j = 0; j < 4; ++j)
        acc[i][j] = __builtin_amdgcn_mfma_f32_16x16x32_bf16(a[i], b[j], acc[i][j], 0, 0, 0);
    __syncthreads();
  }

  if (TRANS) {
    float* C = (float*)Cv;
#pragma unroll
    for (int i = 0; i < 4; ++i)
#pragma unroll
      for (int j = 0; j < 4; ++j)
#pragma unroll
        for (int r = 0; r < 4; ++r) {
          int m = m0 + wr * 64 + i * 16 + lq * 4 + r;
          int n = n0 + wc * 64 + j * 16 + lr;
          C[(size_t)(m & 63) * (TT * NOUT) + (size_t)(m >> 6) * NOUT + n] = acc[i][j][r];
        }
  } else {
    unsigned short* C = (unsigned short*)Cv;
#pragma unroll
    for (int i = 0; i < 4; ++i)
#pragma unroll
      for (int j = 0; j < 4; ++j)
#pragma unroll
        for (int r = 0; r < 4; ++r) {
          int m = m0 + wr * 64 + i * 16 + lq * 4 + r;
          int n = n0 + wc * 64 + j * 16 + lr;
          unsigned short v = f2bf(acc[i][j][r]);
          size_t sl = sl_idx8(m, n);
          C[sl] = (unsigned short)(v & 0x7fffu);  // |P|: signs cleared = "not ready"
          unsigned long long bal = __ballot((v & 0x8000u) != 0);
          if ((l & 7) == 0)  // one lane per 8-elem granule writes the sign byte
            plane[sl >> 3] = (unsigned char)((bal >> (l & ~7)) & 0xffull);
        }
  }
}

// ---------------- persistent recurrence kernel (8 chains x 32 j-blocks) ----------
// block: g = bid&7 (chain, b-rows g*8..+8), jb = bid>>3 (j-cols jb*64..+64).
// 8 waves = kg(4, k-quarters of 512) x jh(2, j-halves of 32). W_hh for the block's
// 64 j x 2048 k lives in wreg[2][16] (per wave: its two 16-j tiles x its k-quarter).
// Per step: all 512 threads stage h_{t-1} (chain's 8 rows x 2048 k = 32KB, 64B/thread,
// tag-validated bypass loads) into swizzled LDS -> barrier -> each wave 16 ds_read_b128
// A-frags + 32 MFMAs -> red LDS -> barrier -> waves 0/1 reduce 4kg + lossless P, relu,
// tag, 8B write-through store, flag (NO drain), prefetch next |P|.
__global__ __launch_bounds__(512, 2) void rnn_recur(unsigned short* __restrict__ hseq,
                                                    const unsigned char* __restrict__ plane,
                                                    const float* __restrict__ Whh,
                                                    unsigned* __restrict__ flags) {
  __shared__ u4 hs[8 * 256];          // 32 KiB h-stage: [row 8][16B-chunk 256], chunk^row swz
  __shared__ float red[2][4][8][68];  // 17 KiB: [buf][kg][row 8][j 64 pad 68]
  const int t = threadIdx.x;
  const int bid = (int)blockIdx.x;
  const int g = bid & 7;
  const int jb = bid >> 3;
  const int j0 = jb * 64;

  const int l = t & 63, w = t >> 6;
  const int lr = l & 15, lq = l >> 4;
  const int kg = w >> 1, jh = w & 1;

  // one-time: W_hh -> registers. wreg[jt][ks]: j-row (j0 + jh*32 + jt*16 + lr),
  // k = kg*512 + ks*32 + lq*8 .. +8 (f32 -> bf16)
  u4 wreg[2][16];
#pragma unroll
  for (int jt = 0; jt < 2; ++jt) {
    const float* p0 = Whh + (size_t)(j0 + jh * 32 + jt * 16 + lr) * NH + kg * 512 + lq * 8;
#pragma unroll
    for (int ks = 0; ks < 16; ++ks) {
      const float* p = p0 + ks * 32;
      float4 v0 = *(const float4*)p;
      float4 v1 = *(const float4*)(p + 4);
      float f[8] = {v0.x, v0.y, v0.z, v0.w, v1.x, v1.y, v1.z, v1.w};
      wreg[jt][ks] = pack8(f);
    }
  }

  char* hb = (char*)hseq;
  const u4 msk = {0x7fff7fffu, 0x7fff7fffu, 0x7fff7fffu, 0x7fff7fffu};

  // writer lane roles (waves 0/1, jh == w): lane -> row l>>3 (0..7), j-quad l&7
  const size_t wbyte = (size_t)(l >> 3) * 128 + (size_t)jh * 64 + (size_t)(l & 7) * 8;
  // stage roles: thread t -> slice jb'=t>>4, row (t&15)>>1, j-half t&1, 4 x 16B chunks
  const int sr = (t & 15) >> 1;
  const int scb = ((t >> 4) << 3) + (t & 1) * 4;
  // per-thread flag to poll (the producer sub-slice this thread stages)
  const int fidx = (g * 32 + (t >> 4)) * 2 + (t & 1);

  unsigned long long pre = 0;  // |P| for next step (4 bf16), writer waves only
  unsigned nib = 0;            // its 4 sign bits

  if (w < 2) {
    // h_0 = relu(P_0) from |P| + sign nibble; tagged write-through; flag=1 (no drain)
    size_t e0 = (((size_t)g * 32 + jb) << 10) + wbyte;
    unsigned long long p0 = __hip_atomic_load((const unsigned long long*)(hb + e0),
                                              __ATOMIC_RELAXED, __HIP_MEMORY_SCOPE_AGENT);
    unsigned nib0 = (plane[e0 >> 4] >> (((e0 >> 3) & 1) * 4)) & 0xfu;
    unsigned long long hv = 0x8000800080008000ull;  // tag all 4
#pragma unroll
    for (int i = 0; i < 4; ++i)
      if (!((nib0 >> i) & 1u)) hv |= ((p0 >> (16 * i)) & 0x7fffull) << (16 * i);
    __hip_atomic_store((unsigned long long*)(hb + e0), hv, __ATOMIC_RELAXED,
                       __HIP_MEMORY_SCOPE_AGENT);
    if (l == 0)
      __hip_atomic_store(flags + ((g * 32 + jb) * 2 + w), 1u, __ATOMIC_RELAXED,
                         __HIP_MEMORY_SCOPE_AGENT);
    size_t e1 = (((size_t)(1 * 8 + g) * 32 + jb) << 10) + wbyte;
    pre = __hip_atomic_load((const unsigned long long*)(hb + e1), __ATOMIC_RELAXED,
                            __HIP_MEMORY_SCOPE_AGENT);
    nib = (plane[e1 >> 4] >> (((e1 >> 3) & 1) * 4)) & 0xfu;
  }

  for (int ts = 1; ts < TT; ++ts) {
    // ---- poll flag hint (1 flag/thread, wave-ballot) ----
    {
      const unsigned* fp = flags + fidx;
      long spins = 0;
      for (;;) {
        unsigned fv = __hip_atomic_load(fp, __ATOMIC_RELAXED, __HIP_MEMORY_SCOPE_AGENT);
        if (__ballot(fv >= (unsigned)ts) == ~0ull) break;
        __builtin_amdgcn_s_sleep(1);
        if (++spins > (1L << 22)) break;  // hang safety
      }
    }
    asm volatile("" ::: "memory");

    // ---- stage h_{ts-1}: 4 x 16B tag-validated bypass loads per thread ----
    const size_t goff = ((((size_t)(ts - 1) * 8 + g) * 32) << 10) + (size_t)t * 64;
    unsigned long long ga = (unsigned long long)(uintptr_t)(hb + goff);
    u4 av[4];
    {
      long att = 0;
      for (;;) {
        asm volatile(
            "global_load_dwordx4 %0, %4, off sc0 sc1\n\t"
            "global_load_dwordx4 %1, %4, off offset:16 sc0 sc1\n\t"
            "global_load_dwordx4 %2, %4, off offset:32 sc0 sc1\n\t"
            "global_load_dwordx4 %3, %4, off offset:48 sc0 sc1\n\t"
            "s_waitcnt vmcnt(0)"
            : "=&v"(av[0]), "=&v"(av[1]), "=&v"(av[2]), "=&v"(av[3])
            : "v"(ga)
            : "memory");
        unsigned am = 0xffffffffu;
#pragma unroll
        for (int c = 0; c < 4; ++c)
#pragma unroll
          for (int d = 0; d < 4; ++d) am &= av[c][d];
        bool ok = (am & 0x80008000u) == 0x80008000u;  // all signs set -> fresh h
        if (__ballot(ok) == ~0ull) break;
        __builtin_amdgcn_s_sleep(1);
        if (++att > (1L << 20)) break;  // hang safety
      }
    }
#pragma unroll
    for (int ch = 0; ch < 4; ++ch)
      hs[sr * 256 + ((scb + ch) ^ sr)] = av[ch] & msk;  // strip tags at stage time
    __syncthreads();

    // ---- A-frags from LDS + 32 MFMAs (2 j-tiles x 16 k-steps) ----
    const int arow = l & 7;  // rows 8..15 of the MFMA tile duplicate rows 0..7
    f4 aA0 = {}, aA1 = {}, aB0 = {}, aB1 = {};
#pragma unroll
    for (int ks = 0; ks < 16; ++ks) {
      u4 a = hs[arow * 256 + ((kg * 64 + ks * 4 + lq) ^ arow)];
      bf8 af = __builtin_bit_cast(bf8, a);
      bf8 b0 = __builtin_bit_cast(bf8, wreg[0][ks]);
      bf8 b1 = __builtin_bit_cast(bf8, wreg[1][ks]);
      if (ks & 1) {
        aA1 = __builtin_amdgcn_mfma_f32_16x16x32_bf16(af, b0, aA1, 0, 0, 0);
        aB1 = __builtin_amdgcn_mfma_f32_16x16x32_bf16(af, b1, aB1, 0, 0, 0);
      } else {
        aA0 = __builtin_amdgcn_mfma_f32_16x16x32_bf16(af, b0, aA0, 0, 0, 0);
        aB0 = __builtin_amdgcn_mfma_f32_16x16x32_bf16(af, b1, aB0, 0, 0, 0);
      }
    }
    f4 aA = aA0 + aA1, aB = aB0 + aB1;

    const int buf = ts & 1;
    if (lq < 2) {  // real rows 0..7 only (C row = lq*4+i)
#pragma unroll
      for (int i = 0; i < 4; ++i) {
        red[buf][kg][lq * 4 + i][jh * 32 + lr] = aA[i];
        red[buf][kg][lq * 4 + i][jh * 32 + 16 + lr] = aB[i];
      }
    }
    __syncthreads();

    // ---- writer epilogue (waves 0/1) ----
    if (w < 2) {
      __builtin_amdgcn_s_setprio(1);
      float pf[4];
#pragma unroll
      for (int i = 0; i < 4; ++i) {
        unsigned pv = (unsigned)((pre >> (16 * i)) & 0xffffull);
        pv |= ((nib >> i) & 1u) << 15;  // lossless sign restore
        pf[i] = bf2f((unsigned short)pv);
      }
      const int rr = l >> 3;
      const int jq = l & 7;
      f4 s = {};
#pragma unroll
      for (int q = 0; q < 4; ++q) s += *(const f4*)&red[buf][q][rr][jh * 32 + jq * 4];
      unsigned long long hv = 0;
#pragma unroll
      for (int i = 0; i < 4; ++i) {
        float v = s[i] + pf[i];
        v = v > 0.f ? v : 0.f;
        hv |= (unsigned long long)(unsigned short)(f2bf(v) | 0x8000u) << (16 * i);
      }
      size_t eo = (((size_t)ts * 8 + g) * 32 + jb) * 1024 + wbyte;
      __hip_atomic_store((unsigned long long*)(hb + eo), hv, __ATOMIC_RELAXED,
                         __HIP_MEMORY_SCOPE_AGENT);
      // flag IMMEDIATELY (no drain) -- consumers validate data by tag
      if (l == 0)
        __hip_atomic_store(flags + ((g * 32 + jb) * 2 + w), (unsigned)(ts + 1),
                           __ATOMIC_RELAXED, __HIP_MEMORY_SCOPE_AGENT);
      if (ts + 1 < TT) {
        size_t en = (((size_t)(ts + 1) * 8 + g) * 32 + jb) * 1024 + wbyte;
        pre = __hip_atomic_load((const unsigned long long*)(hb + en), __ATOMIC_RELAXED,
                                __HIP_MEMORY_SCOPE_AGENT);
        nib = (plane[en >> 4] >> (((en >> 3) & 1) * 4)) & 0xfu;
      }
      __builtin_amdgcn_s_setprio(0);
    }
  }
}

__global__ void kinit(unsigned* f) { f[threadIdx.x] = 0u; }

extern "C" void kernel_launch(void* const* d_in, const int* in_sizes, int n_in,
                              void* d_out, int out_size, void* d_ws, size_t ws_size,
                              hipStream_t stream) {
  const float* xs = (const float*)d_in[0];
  const float* Wih = (const float*)d_in[1];
  const float* Whh = (const float*)d_in[2];
  const float* Wout = (const float*)d_in[3];

  unsigned short* hseq = (unsigned short*)d_ws;  // [TT][8][32][8][64] bf16 = 128 MiB
  unsigned char* plane = (unsigned char*)d_ws + ((size_t)TT * BB * NH * 2);  // 8 MiB
  unsigned* flags = (unsigned*)(plane + ((size_t)TT * BB * NH / 8));         // 512 x u32

  kinit<<<1, 512, 0, stream>>>(flags);

  // phase 1: |P| = |xs @ W_ih^T| -> sliced layout; signs -> plane (lossless)
  gemm_bt<false, false><<<(TT * BB / 128) * (NH / 128), 256, 0, stream>>>(
      (const void*)xs, Wih, (void*)hseq, plane, TT * BB, NH, NIN);

  // phase 2: recurrence (J=64, LDS-dedup staging, reg-resident W_hh)
  rnn_recur<<<256, 512, 0, stream>>>(hseq, plane, Whh, flags);

  // phase 3: out[b][t][o] = h_seq @ W_out^T (strips tags)
  gemm_bt<true, true><<<(TT * BB / 128) * (NOUT / 128), 256, 0, stream>>>(
      (const void*)hseq, Wout, d_out, plane, TT * BB, NOUT, NH);
}

// Round 15
// 4605.088 us; speedup vs baseline: 1.0910x; 1.0910x over previous
//
#include <hip/hip_runtime.h>
#include <hip/hip_bf16.h>
#include <stdint.h>

// RNN: h_t = relu(xs_t @ W_ih^T + h_{t-1} @ W_hh^T); ys = (h_seq @ W_out^T) -> [B,T,O]
// R15 = R12 + streamed consumption: the monolithic 16-load + vmcnt(0) batch becomes
// issue-all-16 -> grouped counted waits vmcnt(12/8/4/0) with tag-check + MFMA per group
// (MFMA overlaps later arrivals), plus surgical 16B fixup for rare stale chunks.
// Everything else identical to R12 (4 chains x 64 blocks, flag hint, no producer drain,
// lossless |P| + sign-plane).

#define TT 512
#define BB 64
#define NIN 1024
#define NH 2048
#define NOUT 1024

typedef __attribute__((ext_vector_type(8))) short bf8;
typedef __attribute__((ext_vector_type(4))) float f4;
typedef __attribute__((ext_vector_type(4))) unsigned int u4;

static __device__ __forceinline__ unsigned short f2bf(float f) {
  __hip_bfloat16 h = __float2bfloat16(f);
  return __builtin_bit_cast(unsigned short, h);
}
static __device__ __forceinline__ float bf2f(unsigned short v) {
  return __bfloat162float(__builtin_bit_cast(__hip_bfloat16, v));
}
static __device__ __forceinline__ u4 pack8(const float* f) {
  u4 r;
#pragma unroll
  for (int i = 0; i < 4; ++i) {
    unsigned lo = f2bf(f[2 * i]);
    unsigned hi = f2bf(f[2 * i + 1]);
    r[i] = lo | (hi << 16);
  }
  return r;
}

// sliced layout: (m = t*64+b, col) -> [t][g=b>>4][jb=col>>5][r=b&15][jl=col&31]
static __device__ __forceinline__ size_t sl_idx(int m, int col) {
  return ((((size_t)(m >> 6) * 4 + ((m & 63) >> 4)) * 64 + (col >> 5)) << 9) +
         (size_t)((m & 63) & 15) * 32 + (col & 31);
}

// ---------------- generic C[M,N] = A[M,K] * B[N,K]^T (bf16 MFMA) ----------------
// <false,false>: phase 1 — store |P| (signs cleared) + sign bits into plane (1b/elem).
// <true,true>:   phase 3 — A = tagged h (strip signs), store f32 out[b][t][n].
template <bool ABF, bool TRANS>
__global__ void gemm_bt(const void* __restrict__ Av, const float* __restrict__ Bw,
                        void* __restrict__ Cv, unsigned char* __restrict__ plane,
                        int M, int N, int K) {
  constexpr int BM = 128, BN = 128, BK = 32;
  __shared__ u4 As[BM * 4];
  __shared__ u4 Bs[BN * 4];
  const int nt = N / BN;
  const int mi = (int)blockIdx.x / nt;
  const int ni = (int)blockIdx.x % nt;
  const int m0 = mi * BM, n0 = ni * BN;
  const int t = threadIdx.x;
  const int l = t & 63, w = t >> 6, wr = w >> 1, wc = w & 1;
  const int lr = l & 15, lq = l >> 4;

  f4 acc[4][4] = {};

  const int srow = t >> 1;
  const int sc0 = (t & 1) * 2;
  const u4 msk = {0x7fff7fffu, 0x7fff7fffu, 0x7fff7fffu, 0x7fff7fffu};

  for (int kt = 0; kt < K; kt += BK) {
    if (ABF) {
      const unsigned short* A = (const unsigned short*)Av;
#pragma unroll
      for (int cc = 0; cc < 2; ++cc) {
        int c = sc0 + cc;
        u4 v = *(const u4*)(A + sl_idx(m0 + srow, kt + c * 8));
        v &= msk;  // strip h tag signs
        As[srow * 4 + (c ^ ((srow ^ (srow >> 2)) & 3))] = v;
      }
    } else {
      const float* A = (const float*)Av;
#pragma unroll
      for (int cc = 0; cc < 2; ++cc) {
        int c = sc0 + cc;
        const float* p = A + (size_t)(m0 + srow) * K + kt + c * 8;
        float4 v0 = *(const float4*)p;
        float4 v1 = *(const float4*)(p + 4);
        float f[8] = {v0.x, v0.y, v0.z, v0.w, v1.x, v1.y, v1.z, v1.w};
        As[srow * 4 + (c ^ ((srow ^ (srow >> 2)) & 3))] = pack8(f);
      }
    }
#pragma unroll
    for (int cc = 0; cc < 2; ++cc) {
      int c = sc0 + cc;
      const float* p = Bw + (size_t)(n0 + srow) * K + kt + c * 8;
      float4 v0 = *(const float4*)p;
      float4 v1 = *(const float4*)(p + 4);
      float f[8] = {v0.x, v0.y, v0.z, v0.w, v1.x, v1.y, v1.z, v1.w};
      Bs[srow * 4 + (c ^ ((srow ^ (srow >> 2)) & 3))] = pack8(f);
    }
    __syncthreads();

    bf8 a[4], b[4];
#pragma unroll
    for (int i = 0; i < 4; ++i) {
      int ra = wr * 64 + i * 16 + lr;
      a[i] = __builtin_bit_cast(bf8, As[ra * 4 + (lq ^ ((ra ^ (ra >> 2)) & 3))]);
      int rb = wc * 64 + i * 16 + lr;
      b[i] = __builtin_bit_cast(bf8, Bs[rb * 4 + (lq ^ ((rb ^ (rb >> 2)) & 3))]);
    }
#pragma unroll
    for (int i = 0; i < 4; ++i)
#pragma unroll
      for (int j = 0; j < 4; ++j)
        acc[i][j] = __builtin_amdgcn_mfma_f32_16x16x32_bf16(a[i], b[j], acc[i][j], 0, 0, 0);
    __syncthreads();
  }

  if (TRANS) {
    float* C = (float*)Cv;
#pragma unroll
    for (int i = 0; i < 4; ++i)
#pragma unroll
      for (int j = 0; j < 4; ++j)
#pragma unroll
        for (int r = 0; r < 4; ++r) {
          int m = m0 + wr * 64 + i * 16 + lq * 4 + r;
          int n = n0 + wc * 64 + j * 16 + lr;
          C[(size_t)(m & 63) * (TT * NOUT) + (size_t)(m >> 6) * NOUT + n] = acc[i][j][r];
        }
  } else {
    unsigned short* C = (unsigned short*)Cv;
#pragma unroll
    for (int i = 0; i < 4; ++i)
#pragma unroll
      for (int j = 0; j < 4; ++j)
#pragma unroll
        for (int r = 0; r < 4; ++r) {
          int m = m0 + wr * 64 + i * 16 + lq * 4 + r;
          int n = n0 + wc * 64 + j * 16 + lr;
          unsigned short v = f2bf(acc[i][j][r]);
          size_t sl = sl_idx(m, n);
          C[sl] = (unsigned short)(v & 0x7fffu);  // |P|: signs cleared = "not ready"
          unsigned long long bal = __ballot((v & 0x8000u) != 0);
          if ((l & 7) == 0)  // one lane per 8-elem granule writes the sign byte
            plane[sl >> 3] = (unsigned char)((bal >> (l & ~7)) & 0xffull);
        }
  }
}

// ---------------- persistent recurrence kernel (4 chains x 64 blocks) ------------
// block: g = (bid&7)>>1 (chain, rows g*16..+16), jb = (bid>>3)*2+(bid&1) (cols jb*32..+32).
// 8 waves = kg(4) x jh(2). Waves 0/1 are writers (jh=w). Producer: store tagged h
// (write-through) -> flag IMMEDIATELY (no drain). Consumer: poll flag -> issue 16 loads
// -> grouped vmcnt(12/8/4/0) waits with tag-check + MFMA per group -> stale fixup.
__global__ __launch_bounds__(512, 2) void rnn_recur(unsigned short* __restrict__ hseq,
                                                    const unsigned char* __restrict__ plane,
                                                    const float* __restrict__ Whh,
                                                    unsigned* __restrict__ flags) {
  __shared__ u4 Wl[32 * 256];          // 128 KiB: [j_local 32][k-chunk 256], chunk ^ (j&7)
  __shared__ float red[2][4][16][36];  // 18 KiB: [buf][kg][row][j 32 pad 36]
  const int t = threadIdx.x;
  const int bid = (int)blockIdx.x;
  const int g = (bid & 7) >> 1;
  const int jb = ((bid >> 3) << 1) | (bid & 1);
  const int j0 = jb * 32;

  // one-time: W_hh j-slice (32 rows x 2048) -> swizzled LDS (f32 -> bf16)
  {
    const int jl = t >> 4;
    const int ci = t & 15;
#pragma unroll
    for (int q = 0; q < 16; ++q) {
      int cc = ci * 16 + q;
      const float* p = Whh + (size_t)(j0 + jl) * NH + cc * 8;
      float4 v0 = *(const float4*)p;
      float4 v1 = *(const float4*)(p + 4);
      float f[8] = {v0.x, v0.y, v0.z, v0.w, v1.x, v1.y, v1.z, v1.w};
      Wl[jl * 256 + (cc ^ (jl & 7))] = pack8(f);
    }
  }

  const int l = t & 63, w = t >> 6;
  const int lr = l & 15, lq = l >> 4;
  const int kg = w >> 1, jh = w & 1;

  char* hb = (char*)hseq;
  const size_t gofs = (size_t)g << 16;
  const u4 msk = {0x7fff7fffu, 0x7fff7fffu, 0x7fff7fffu, 0x7fff7fffu};

  // writer lane roles (waves 0/1, jh == w): 64 lanes = 16 rows x 4 j-quads (4 elems)
  const int wr_r = l >> 2;
  const int wjq = l & 3;
  const size_t wbyte = (size_t)wr_r * 64 + jh * 32 + wjq * 8;

  unsigned long long pre = 0;  // |P| for next step (4 bf16), writer waves only
  unsigned nib = 0;            // its 4 sign bits

  __syncthreads();  // Wl ready

  if (w < 2) {
    // h_0 = relu(P_0) from |P| + sign nibble; tagged write-through; flag=1 (NO drain)
    size_t e0 = gofs + ((size_t)jb << 10) + wbyte;
    unsigned long long p0 = __hip_atomic_load((const unsigned long long*)(hb + e0),
                                              __ATOMIC_RELAXED, __HIP_MEMORY_SCOPE_AGENT);
    unsigned nib0 = (plane[e0 >> 4] >> (((e0 >> 3) & 1) * 4)) & 0xfu;
    unsigned long long hv = 0x8000800080008000ull;  // tag all 4
#pragma unroll
    for (int i = 0; i < 4; ++i)
      if (!((nib0 >> i) & 1u)) hv |= ((p0 >> (16 * i)) & 0x7fffull) << (16 * i);
    __hip_atomic_store((unsigned long long*)(hb + e0), hv, __ATOMIC_RELAXED,
                       __HIP_MEMORY_SCOPE_AGENT);
    if (l == 0)
      __hip_atomic_store(flags + ((g * 64 + jb) * 2 + w), 1u, __ATOMIC_RELAXED,
                         __HIP_MEMORY_SCOPE_AGENT);
    size_t e1 = ((size_t)4 << 16) + gofs + ((size_t)jb << 10) + wbyte;
    pre = __hip_atomic_load((const unsigned long long*)(hb + e1), __ATOMIC_RELAXED,
                            __HIP_MEMORY_SCOPE_AGENT);
    nib = (plane[e1 >> 4] >> (((e1 >> 3) & 1) * 4)) & 0xfu;
  }

  for (int ts = 1; ts < TT; ++ts) {
    // poll the 32 producer-half flags covering this wave's k-quarter (hint only)
    {
      const unsigned* fp = flags + ((g * 64 + kg * 16 + (l >> 1)) * 2 + (l & 1));
      long spins = 0;
      for (;;) {
        unsigned fv = (l < 32) ? __hip_atomic_load(fp, __ATOMIC_RELAXED,
                                                   __HIP_MEMORY_SCOPE_AGENT)
                               : 0xffffffffu;
        if (__ballot(fv >= (unsigned)ts) == ~0ull) break;
        __builtin_amdgcn_s_sleep(1);
        if (++spins > (1L << 22)) break;  // hang safety
      }
    }
    asm volatile("" ::: "memory");  // keep data loads below the spin

    // issue 16 chunk loads (bypass); NO monolithic wait
    const size_t rowoff = (size_t)(l & 15) * 64 + (size_t)(l >> 4) * 16;
    const size_t base =
        (((size_t)(ts - 1) * 4) << 16) + gofs + ((size_t)(kg * 16) << 10) + rowoff;
    unsigned long long a0 = (unsigned long long)(uintptr_t)(hb + base);
    unsigned long long a1 = a0 + 4096;
    unsigned long long a2 = a0 + 8192;
    unsigned long long a3 = a0 + 12288;
    u4 av[16];
    asm volatile(
        "global_load_dwordx4 %0, %16, off sc0 sc1\n\t"
        "global_load_dwordx4 %1, %16, off offset:1024 sc0 sc1\n\t"
        "global_load_dwordx4 %2, %16, off offset:2048 sc0 sc1\n\t"
        "global_load_dwordx4 %3, %16, off offset:3072 sc0 sc1\n\t"
        "global_load_dwordx4 %4, %17, off sc0 sc1\n\t"
        "global_load_dwordx4 %5, %17, off offset:1024 sc0 sc1\n\t"
        "global_load_dwordx4 %6, %17, off offset:2048 sc0 sc1\n\t"
        "global_load_dwordx4 %7, %17, off offset:3072 sc0 sc1\n\t"
        "global_load_dwordx4 %8, %18, off sc0 sc1\n\t"
        "global_load_dwordx4 %9, %18, off offset:1024 sc0 sc1\n\t"
        "global_load_dwordx4 %10, %18, off offset:2048 sc0 sc1\n\t"
        "global_load_dwordx4 %11, %18, off offset:3072 sc0 sc1\n\t"
        "global_load_dwordx4 %12, %19, off sc0 sc1\n\t"
        "global_load_dwordx4 %13, %19, off offset:1024 sc0 sc1\n\t"
        "global_load_dwordx4 %14, %19, off offset:2048 sc0 sc1\n\t"
        "global_load_dwordx4 %15, %19, off offset:3072 sc0 sc1"
        : "=&v"(av[0]), "=&v"(av[1]), "=&v"(av[2]), "=&v"(av[3]),
          "=&v"(av[4]), "=&v"(av[5]), "=&v"(av[6]), "=&v"(av[7]),
          "=&v"(av[8]), "=&v"(av[9]), "=&v"(av[10]), "=&v"(av[11]),
          "=&v"(av[12]), "=&v"(av[13]), "=&v"(av[14]), "=&v"(av[15])
        : "v"(a0), "v"(a1), "v"(a2), "v"(a3)
        : "memory");

    f4 acc0 = {}, acc1 = {};
    unsigned stale = 0;

#define CHK(c)                                                                        \
  {                                                                                   \
    unsigned am_ = av[c][0] & av[c][1] & av[c][2] & av[c][3];                         \
    if (__ballot((am_ & 0x80008000u) == 0x80008000u) == ~0ull) {                      \
      u4 v_ = av[c] & msk;                                                            \
      bf8 af_ = __builtin_bit_cast(bf8, v_);                                          \
      int ci_ = kg * 64 + (c) * 4 + lq;                                               \
      bf8 bf_ = __builtin_bit_cast(bf8, Wl[(jh * 16 + lr) * 256 + (ci_ ^ (lr & 7))]); \
      if ((c) & 1)                                                                    \
        acc1 = __builtin_amdgcn_mfma_f32_16x16x32_bf16(af_, bf_, acc1, 0, 0, 0);      \
      else                                                                            \
        acc0 = __builtin_amdgcn_mfma_f32_16x16x32_bf16(af_, bf_, acc0, 0, 0, 0);      \
    } else                                                                            \
      stale |= 1u << (c);                                                             \
  }

    // grouped counted waits: consume earliest arrivals while later loads fly
    asm volatile("s_waitcnt vmcnt(12)"
                 : "+v"(av[0]), "+v"(av[1]), "+v"(av[2]), "+v"(av[3]));
    __builtin_amdgcn_sched_barrier(0);
    CHK(0) CHK(1) CHK(2) CHK(3)
    asm volatile("s_waitcnt vmcnt(8)"
                 : "+v"(av[4]), "+v"(av[5]), "+v"(av[6]), "+v"(av[7]));
    __builtin_amdgcn_sched_barrier(0);
    CHK(4) CHK(5) CHK(6) CHK(7)
    asm volatile("s_waitcnt vmcnt(4)"
                 : "+v"(av[8]), "+v"(av[9]), "+v"(av[10]), "+v"(av[11]));
    __builtin_amdgcn_sched_barrier(0);
    CHK(8) CHK(9) CHK(10) CHK(11)
    asm volatile("s_waitcnt vmcnt(0)"
                 : "+v"(av[12]), "+v"(av[13]), "+v"(av[14]), "+v"(av[15]));
    __builtin_amdgcn_sched_barrier(0);
    CHK(12) CHK(13) CHK(14) CHK(15)
#undef CHK

    // fixup: surgical 16B re-loads of rare stale chunks (no-drain window)
    {
      long att = 0;
      while (stale) {
        int c = __builtin_ctz(stale);
        unsigned long long ad =
            a0 + (unsigned long long)(c >> 2) * 4096ull + (unsigned long long)(c & 3) * 1024ull;
        for (;;) {
          asm volatile(
              "global_load_dwordx4 %0, %1, off sc0 sc1\n\t"
              "s_waitcnt vmcnt(0)"
              : "=&v"(av[c])
              : "v"(ad)
              : "memory");
          unsigned am_ = av[c][0] & av[c][1] & av[c][2] & av[c][3];
          if (__ballot((am_ & 0x80008000u) == 0x80008000u) == ~0ull) break;
          __builtin_amdgcn_s_sleep(1);
          if (++att > (1L << 20)) break;  // hang safety
        }
        u4 v_ = av[c] & msk;
        bf8 af_ = __builtin_bit_cast(bf8, v_);
        int ci_ = kg * 64 + c * 4 + lq;
        bf8 bf_ = __builtin_bit_cast(bf8, Wl[(jh * 16 + lr) * 256 + (ci_ ^ (lr & 7))]);
        if (c & 1)
          acc1 = __builtin_amdgcn_mfma_f32_16x16x32_bf16(af_, bf_, acc1, 0, 0, 0);
        else
          acc0 = __builtin_amdgcn_mfma_f32_16x16x32_bf16(af_, bf_, acc0, 0, 0, 0);
        stale &= stale - 1;
      }
    }
    f4 a2v = acc0 + acc1;

    const int buf = ts & 1;
#pragma unroll
    for (int i = 0; i < 4; ++i) red[buf][kg][(l >> 4) * 4 + i][jh * 16 + (l & 15)] = a2v[i];
    __syncthreads();

    if (w < 2) {
      __builtin_amdgcn_s_setprio(1);
      float pf[4];
#pragma unroll
      for (int i = 0; i < 4; ++i) {
        unsigned pv = (unsigned)((pre >> (16 * i)) & 0xffffull);
        pv |= ((nib >> i) & 1u) << 15;  // lossless sign restore
        pf[i] = bf2f((unsigned short)pv);
      }
      f4 s = {};
#pragma unroll
      for (int q = 0; q < 4; ++q) s += *(const f4*)&red[buf][q][wr_r][jh * 16 + wjq * 4];
      unsigned long long hv = 0;
#pragma unroll
      for (int i = 0; i < 4; ++i) {
        float v = s[i] + pf[i];
        v = v > 0.f ? v : 0.f;
        hv |= (unsigned long long)(unsigned short)(f2bf(v) | 0x8000u) << (16 * i);
      }
      size_t eo = (((size_t)ts * 4) << 16) + gofs + ((size_t)jb << 10) + wbyte;
      __hip_atomic_store((unsigned long long*)(hb + eo), hv, __ATOMIC_RELAXED,
                         __HIP_MEMORY_SCOPE_AGENT);
      // flag IMMEDIATELY -- no vmcnt drain; consumers validate data by tag
      if (l == 0)
        __hip_atomic_store(flags + ((g * 64 + jb) * 2 + w), (unsigned)(ts + 1),
                           __ATOMIC_RELAXED, __HIP_MEMORY_SCOPE_AGENT);
      if (ts + 1 < TT) {
        size_t en = (((size_t)(ts + 1) * 4) << 16) + gofs + ((size_t)jb << 10) + wbyte;
        pre = __hip_atomic_load((const unsigned long long*)(hb + en), __ATOMIC_RELAXED,
                                __HIP_MEMORY_SCOPE_AGENT);
        nib = (plane[en >> 4] >> (((en >> 3) & 1) * 4)) & 0xfu;
      }
      __builtin_amdgcn_s_setprio(0);
    }
  }
}

__global__ void kinit(unsigned* f) { f[threadIdx.x] = 0u; }

extern "C" void kernel_launch(void* const* d_in, const int* in_sizes, int n_in,
                              void* d_out, int out_size, void* d_ws, size_t ws_size,
                              hipStream_t stream) {
  const float* xs = (const float*)d_in[0];
  const float* Wih = (const float*)d_in[1];
  const float* Whh = (const float*)d_in[2];
  const float* Wout = (const float*)d_in[3];

  unsigned short* hseq = (unsigned short*)d_ws;  // [TT][4][64][16][32] bf16 = 128 MiB
  unsigned char* plane = (unsigned char*)d_ws + ((size_t)TT * BB * NH * 2);  // 8 MiB
  unsigned* flags = (unsigned*)(plane + ((size_t)TT * BB * NH / 8));         // 512 x u32

  kinit<<<1, 512, 0, stream>>>(flags);

  // phase 1: |P| = |xs @ W_ih^T| -> sliced layout; signs -> plane (lossless)
  gemm_bt<false, false><<<(TT * BB / 128) * (NH / 128), 256, 0, stream>>>(
      (const void*)xs, Wih, (void*)hseq, plane, TT * BB, NH, NIN);

  // phase 2: recurrence (flag hint + streamed tag-validated consumption)
  rnn_recur<<<256, 512, 0, stream>>>(hseq, plane, Whh, flags);

  // phase 3: out[b][t][o] = h_seq @ W_out^T (strips tags)
  gemm_bt<true, true><<<(TT * BB / 128) * (NOUT / 128), 256, 0, stream>>>(
      (const void*)hseq, Wout, d_out, plane, TT * BB, NOUT, NH);
}

// Round 16
// 3861.425 us; speedup vs baseline: 1.3011x; 1.1926x over previous
//
#include <hip/hip_runtime.h>
#include <hip/hip_bf16.h>
#include <stdint.h>

// RNN: h_t = relu(xs_t @ W_ih^T + h_{t-1} @ W_hh^T); ys = (h_seq @ W_out^T) -> [B,T,O]
// R16 = R12 verbatim (measured best: 3.835 ms total; recur 3.40 ms = 6.65 us/step).
// Final configuration. Structure: 4 independent chains (16 b-rows) x 64 j-blocks;
// flag-hint + tag-validated data (all bf16 sign bits set on h; h>=0 so signs are free),
// NO producer drain; lossless |P| via sign-plane; 16-deep bypass load MLP.
// 15 rounds of single-variable experiments establish the remaining cost as the
// serialized device-scope visibility+gather quantum (~16k cycles/step) of the 511
// inherently serial exchange rounds -- a latency floor, not a BW/compute ceiling.

#define TT 512
#define BB 64
#define NIN 1024
#define NH 2048
#define NOUT 1024

typedef __attribute__((ext_vector_type(8))) short bf8;
typedef __attribute__((ext_vector_type(4))) float f4;
typedef __attribute__((ext_vector_type(4))) unsigned int u4;

static __device__ __forceinline__ unsigned short f2bf(float f) {
  __hip_bfloat16 h = __float2bfloat16(f);
  return __builtin_bit_cast(unsigned short, h);
}
static __device__ __forceinline__ float bf2f(unsigned short v) {
  return __bfloat162float(__builtin_bit_cast(__hip_bfloat16, v));
}
static __device__ __forceinline__ u4 pack8(const float* f) {
  u4 r;
#pragma unroll
  for (int i = 0; i < 4; ++i) {
    unsigned lo = f2bf(f[2 * i]);
    unsigned hi = f2bf(f[2 * i + 1]);
    r[i] = lo | (hi << 16);
  }
  return r;
}

// sliced layout: (m = t*64+b, col) -> [t][g=b>>4][jb=col>>5][r=b&15][jl=col&31]
static __device__ __forceinline__ size_t sl_idx(int m, int col) {
  return ((((size_t)(m >> 6) * 4 + ((m & 63) >> 4)) * 64 + (col >> 5)) << 9) +
         (size_t)((m & 63) & 15) * 32 + (col & 31);
}

// ---------------- generic C[M,N] = A[M,K] * B[N,K]^T (bf16 MFMA) ----------------
// <false,false>: phase 1 — store |P| (signs cleared) + sign bits into plane (1b/elem).
// <true,true>:   phase 3 — A = tagged h (strip signs), store f32 out[b][t][n].
template <bool ABF, bool TRANS>
__global__ void gemm_bt(const void* __restrict__ Av, const float* __restrict__ Bw,
                        void* __restrict__ Cv, unsigned char* __restrict__ plane,
                        int M, int N, int K) {
  constexpr int BM = 128, BN = 128, BK = 32;
  __shared__ u4 As[BM * 4];
  __shared__ u4 Bs[BN * 4];
  const int nt = N / BN;
  const int mi = (int)blockIdx.x / nt;
  const int ni = (int)blockIdx.x % nt;
  const int m0 = mi * BM, n0 = ni * BN;
  const int t = threadIdx.x;
  const int l = t & 63, w = t >> 6, wr = w >> 1, wc = w & 1;
  const int lr = l & 15, lq = l >> 4;

  f4 acc[4][4] = {};

  const int srow = t >> 1;
  const int sc0 = (t & 1) * 2;
  const u4 msk = {0x7fff7fffu, 0x7fff7fffu, 0x7fff7fffu, 0x7fff7fffu};

  for (int kt = 0; kt < K; kt += BK) {
    if (ABF) {
      const unsigned short* A = (const unsigned short*)Av;
#pragma unroll
      for (int cc = 0; cc < 2; ++cc) {
        int c = sc0 + cc;
        u4 v = *(const u4*)(A + sl_idx(m0 + srow, kt + c * 8));
        v &= msk;  // strip h tag signs
        As[srow * 4 + (c ^ ((srow ^ (srow >> 2)) & 3))] = v;
      }
    } else {
      const float* A = (const float*)Av;
#pragma unroll
      for (int cc = 0; cc < 2; ++cc) {
        int c = sc0 + cc;
        const float* p = A + (size_t)(m0 + srow) * K + kt + c * 8;
        float4 v0 = *(const float4*)p;
        float4 v1 = *(const float4*)(p + 4);
        float f[8] = {v0.x, v0.y, v0.z, v0.w, v1.x, v1.y, v1.z, v1.w};
        As[srow * 4 + (c ^ ((srow ^ (srow >> 2)) & 3))] = pack8(f);
      }
    }
#pragma unroll
    for (int cc = 0; cc < 2; ++cc) {
      int c = sc0 + cc;
      const float* p = Bw + (size_t)(n0 + srow) * K + kt + c * 8;
      float4 v0 = *(const float4*)p;
      float4 v1 = *(const float4*)(p + 4);
      float f[8] = {v0.x, v0.y, v0.z, v0.w, v1.x, v1.y, v1.z, v1.w};
      Bs[srow * 4 + (c ^ ((srow ^ (srow >> 2)) & 3))] = pack8(f);
    }
    __syncthreads();

    bf8 a[4], b[4];
#pragma unroll
    for (int i = 0; i < 4; ++i) {
      int ra = wr * 64 + i * 16 + lr;
      a[i] = __builtin_bit_cast(bf8, As[ra * 4 + (lq ^ ((ra ^ (ra >> 2)) & 3))]);
      int rb = wc * 64 + i * 16 + lr;
      b[i] = __builtin_bit_cast(bf8, Bs[rb * 4 + (lq ^ ((rb ^ (rb >> 2)) & 3))]);
    }
#pragma unroll
    for (int i = 0; i < 4; ++i)
#pragma unroll
      for (int j = 0; j < 4; ++j)
        acc[i][j] = __builtin_amdgcn_mfma_f32_16x16x32_bf16(a[i], b[j], acc[i][j], 0, 0, 0);
    __syncthreads();
  }

  if (TRANS) {
    float* C = (float*)Cv;
#pragma unroll
    for (int i = 0; i < 4; ++i)
#pragma unroll
      for (int j = 0; j < 4; ++j)
#pragma unroll
        for (int r = 0; r < 4; ++r) {
          int m = m0 + wr * 64 + i * 16 + lq * 4 + r;
          int n = n0 + wc * 64 + j * 16 + lr;
          C[(size_t)(m & 63) * (TT * NOUT) + (size_t)(m >> 6) * NOUT + n] = acc[i][j][r];
        }
  } else {
    unsigned short* C = (unsigned short*)Cv;
#pragma unroll
    for (int i = 0; i < 4; ++i)
#pragma unroll
      for (int j = 0; j < 4; ++j)
#pragma unroll
        for (int r = 0; r < 4; ++r) {
          int m = m0 + wr * 64 + i * 16 + lq * 4 + r;
          int n = n0 + wc * 64 + j * 16 + lr;
          unsigned short v = f2bf(acc[i][j][r]);
          size_t sl = sl_idx(m, n);
          C[sl] = (unsigned short)(v & 0x7fffu);  // |P|: signs cleared = "not ready"
          unsigned long long bal = __ballot((v & 0x8000u) != 0);
          if ((l & 7) == 0)  // one lane per 8-elem granule writes the sign byte
            plane[sl >> 3] = (unsigned char)((bal >> (l & ~7)) & 0xffull);
        }
  }
}

// ---------------- persistent recurrence kernel (4 chains x 64 blocks) ------------
// block: g = (bid&7)>>1 (chain, rows g*16..+16), jb = (bid>>3)*2+(bid&1) (cols jb*32..+32).
// 8 waves = kg(4) x jh(2). Waves 0/1 are writers (jh=w). Producer: store tagged h
// (write-through) -> flag IMMEDIATELY (no drain). Consumer: poll flag -> 16-deep loads
// -> tag-check -> rare re-load.
__global__ __launch_bounds__(512, 2) void rnn_recur(unsigned short* __restrict__ hseq,
                                                    const unsigned char* __restrict__ plane,
                                                    const float* __restrict__ Whh,
                                                    unsigned* __restrict__ flags) {
  __shared__ u4 Wl[32 * 256];          // 128 KiB: [j_local 32][k-chunk 256], chunk ^ (j&7)
  __shared__ float red[2][4][16][36];  // 18 KiB: [buf][kg][row][j 32 pad 36]
  const int t = threadIdx.x;
  const int bid = (int)blockIdx.x;
  const int g = (bid & 7) >> 1;
  const int jb = ((bid >> 3) << 1) | (bid & 1);
  const int j0 = jb * 32;

  // one-time: W_hh j-slice (32 rows x 2048) -> swizzled LDS (f32 -> bf16)
  {
    const int jl = t >> 4;
    const int ci = t & 15;
#pragma unroll
    for (int q = 0; q < 16; ++q) {
      int cc = ci * 16 + q;
      const float* p = Whh + (size_t)(j0 + jl) * NH + cc * 8;
      float4 v0 = *(const float4*)p;
      float4 v1 = *(const float4*)(p + 4);
      float f[8] = {v0.x, v0.y, v0.z, v0.w, v1.x, v1.y, v1.z, v1.w};
      Wl[jl * 256 + (cc ^ (jl & 7))] = pack8(f);
    }
  }

  const int l = t & 63, w = t >> 6;
  const int lr = l & 15, lq = l >> 4;
  const int kg = w >> 1, jh = w & 1;

  char* hb = (char*)hseq;
  const size_t gofs = (size_t)g << 16;
  const u4 msk = {0x7fff7fffu, 0x7fff7fffu, 0x7fff7fffu, 0x7fff7fffu};

  // writer lane roles (waves 0/1, jh == w): 64 lanes = 16 rows x 4 j-quads (4 elems)
  const int wr_r = l >> 2;
  const int wjq = l & 3;
  const size_t wbyte = (size_t)wr_r * 64 + jh * 32 + wjq * 8;

  unsigned long long pre = 0;  // |P| for next step (4 bf16), writer waves only
  unsigned nib = 0;            // its 4 sign bits

  __syncthreads();  // Wl ready

  if (w < 2) {
    // h_0 = relu(P_0) from |P| + sign nibble; tagged write-through; flag=1 (NO drain)
    size_t e0 = gofs + ((size_t)jb << 10) + wbyte;
    unsigned long long p0 = __hip_atomic_load((const unsigned long long*)(hb + e0),
                                              __ATOMIC_RELAXED, __HIP_MEMORY_SCOPE_AGENT);
    unsigned nib0 = (plane[e0 >> 4] >> (((e0 >> 3) & 1) * 4)) & 0xfu;
    unsigned long long hv = 0x8000800080008000ull;  // tag all 4
#pragma unroll
    for (int i = 0; i < 4; ++i)
      if (!((nib0 >> i) & 1u)) hv |= ((p0 >> (16 * i)) & 0x7fffull) << (16 * i);
    __hip_atomic_store((unsigned long long*)(hb + e0), hv, __ATOMIC_RELAXED,
                       __HIP_MEMORY_SCOPE_AGENT);
    if (l == 0)
      __hip_atomic_store(flags + ((g * 64 + jb) * 2 + w), 1u, __ATOMIC_RELAXED,
                         __HIP_MEMORY_SCOPE_AGENT);
    size_t e1 = ((size_t)4 << 16) + gofs + ((size_t)jb << 10) + wbyte;
    pre = __hip_atomic_load((const unsigned long long*)(hb + e1), __ATOMIC_RELAXED,
                            __HIP_MEMORY_SCOPE_AGENT);
    nib = (plane[e1 >> 4] >> (((e1 >> 3) & 1) * 4)) & 0xfu;
  }

  for (int ts = 1; ts < TT; ++ts) {
    // poll the 32 producer-half flags covering this wave's k-quarter (hint only)
    {
      const unsigned* fp = flags + ((g * 64 + kg * 16 + (l >> 1)) * 2 + (l & 1));
      long spins = 0;
      for (;;) {
        unsigned fv = (l < 32) ? __hip_atomic_load(fp, __ATOMIC_RELAXED,
                                                   __HIP_MEMORY_SCOPE_AGENT)
                               : 0xffffffffu;
        if (__ballot(fv >= (unsigned)ts) == ~0ull) break;
        __builtin_amdgcn_s_sleep(1);
        if (++spins > (1L << 22)) break;  // hang safety
      }
    }
    asm volatile("" ::: "memory");  // keep data loads below the spin

    // 16 chunk loads (bypass), 16-deep; tag-validated, rare re-load
    const size_t rowoff = (size_t)(l & 15) * 64 + (size_t)(l >> 4) * 16;
    const size_t base =
        (((size_t)(ts - 1) * 4) << 16) + gofs + ((size_t)(kg * 16) << 10) + rowoff;
    unsigned long long a0 = (unsigned long long)(uintptr_t)(hb + base);
    unsigned long long a1 = a0 + 4096;
    unsigned long long a2 = a0 + 8192;
    unsigned long long a3 = a0 + 12288;
    u4 av[16];
    int att = 0;
    for (;;) {
      asm volatile(
          "global_load_dwordx4 %0, %16, off sc0 sc1\n\t"
          "global_load_dwordx4 %1, %16, off offset:1024 sc0 sc1\n\t"
          "global_load_dwordx4 %2, %16, off offset:2048 sc0 sc1\n\t"
          "global_load_dwordx4 %3, %16, off offset:3072 sc0 sc1\n\t"
          "global_load_dwordx4 %4, %17, off sc0 sc1\n\t"
          "global_load_dwordx4 %5, %17, off offset:1024 sc0 sc1\n\t"
          "global_load_dwordx4 %6, %17, off offset:2048 sc0 sc1\n\t"
          "global_load_dwordx4 %7, %17, off offset:3072 sc0 sc1\n\t"
          "global_load_dwordx4 %8, %18, off sc0 sc1\n\t"
          "global_load_dwordx4 %9, %18, off offset:1024 sc0 sc1\n\t"
          "global_load_dwordx4 %10, %18, off offset:2048 sc0 sc1\n\t"
          "global_load_dwordx4 %11, %18, off offset:3072 sc0 sc1\n\t"
          "global_load_dwordx4 %12, %19, off sc0 sc1\n\t"
          "global_load_dwordx4 %13, %19, off offset:1024 sc0 sc1\n\t"
          "global_load_dwordx4 %14, %19, off offset:2048 sc0 sc1\n\t"
          "global_load_dwordx4 %15, %19, off offset:3072 sc0 sc1\n\t"
          "s_waitcnt vmcnt(0)"
          : "=&v"(av[0]), "=&v"(av[1]), "=&v"(av[2]), "=&v"(av[3]),
            "=&v"(av[4]), "=&v"(av[5]), "=&v"(av[6]), "=&v"(av[7]),
            "=&v"(av[8]), "=&v"(av[9]), "=&v"(av[10]), "=&v"(av[11]),
            "=&v"(av[12]), "=&v"(av[13]), "=&v"(av[14]), "=&v"(av[15])
          : "v"(a0), "v"(a1), "v"(a2), "v"(a3)
          : "memory");
      unsigned am = 0xffffffffu;
#pragma unroll
      for (int c = 0; c < 16; ++c)
#pragma unroll
        for (int d = 0; d < 4; ++d) am &= av[c][d];
      bool ok = (am & 0x80008000u) == 0x80008000u;  // every granule tagged -> fresh h
      if (__ballot(ok) == ~0ull) break;
      __builtin_amdgcn_s_sleep(1);
      if (++att > (1 << 20)) break;  // hang safety; never hit when logic is correct
    }

    f4 acc0 = {}, acc1 = {};
#pragma unroll
    for (int c = 0; c < 16; ++c) {
      u4 v = av[c] & msk;  // strip tag signs
      bf8 af = __builtin_bit_cast(bf8, v);
      int ci = kg * 64 + c * 4 + lq;
      bf8 bfr = __builtin_bit_cast(bf8, Wl[(jh * 16 + lr) * 256 + (ci ^ (lr & 7))]);
      if (c & 1)
        acc1 = __builtin_amdgcn_mfma_f32_16x16x32_bf16(af, bfr, acc1, 0, 0, 0);
      else
        acc0 = __builtin_amdgcn_mfma_f32_16x16x32_bf16(af, bfr, acc0, 0, 0, 0);
    }
    f4 a2v = acc0 + acc1;

    const int buf = ts & 1;
#pragma unroll
    for (int i = 0; i < 4; ++i) red[buf][kg][(l >> 4) * 4 + i][jh * 16 + (l & 15)] = a2v[i];
    __syncthreads();

    if (w < 2) {
      __builtin_amdgcn_s_setprio(1);
      float pf[4];
#pragma unroll
      for (int i = 0; i < 4; ++i) {
        unsigned pv = (unsigned)((pre >> (16 * i)) & 0xffffull);
        pv |= ((nib >> i) & 1u) << 15;  // lossless sign restore
        pf[i] = bf2f((unsigned short)pv);
      }
      f4 s = {};
#pragma unroll
      for (int q = 0; q < 4; ++q) s += *(const f4*)&red[buf][q][wr_r][jh * 16 + wjq * 4];
      unsigned long long hv = 0;
#pragma unroll
      for (int i = 0; i < 4; ++i) {
        float v = s[i] + pf[i];
        v = v > 0.f ? v : 0.f;
        hv |= (unsigned long long)(unsigned short)(f2bf(v) | 0x8000u) << (16 * i);
      }
      size_t eo = (((size_t)ts * 4) << 16) + gofs + ((size_t)jb << 10) + wbyte;
      __hip_atomic_store((unsigned long long*)(hb + eo), hv, __ATOMIC_RELAXED,
                         __HIP_MEMORY_SCOPE_AGENT);
      // flag IMMEDIATELY -- no vmcnt drain; consumers validate data by tag
      if (l == 0)
        __hip_atomic_store(flags + ((g * 64 + jb) * 2 + w), (unsigned)(ts + 1),
                           __ATOMIC_RELAXED, __HIP_MEMORY_SCOPE_AGENT);
      if (ts + 1 < TT) {
        size_t en = (((size_t)(ts + 1) * 4) << 16) + gofs + ((size_t)jb << 10) + wbyte;
        pre = __hip_atomic_load((const unsigned long long*)(hb + en), __ATOMIC_RELAXED,
                                __HIP_MEMORY_SCOPE_AGENT);
        nib = (plane[en >> 4] >> (((en >> 3) & 1) * 4)) & 0xfu;
      }
      __builtin_amdgcn_s_setprio(0);
    }
  }
}

__global__ void kinit(unsigned* f) { f[threadIdx.x] = 0u; }

extern "C" void kernel_launch(void* const* d_in, const int* in_sizes, int n_in,
                              void* d_out, int out_size, void* d_ws, size_t ws_size,
                              hipStream_t stream) {
  const float* xs = (const float*)d_in[0];
  const float* Wih = (const float*)d_in[1];
  const float* Whh = (const float*)d_in[2];
  const float* Wout = (const float*)d_in[3];

  unsigned short* hseq = (unsigned short*)d_ws;  // [TT][4][64][16][32] bf16 = 128 MiB
  unsigned char* plane = (unsigned char*)d_ws + ((size_t)TT * BB * NH * 2);  // 8 MiB
  unsigned* flags = (unsigned*)(plane + ((size_t)TT * BB * NH / 8));         // 512 x u32

  kinit<<<1, 512, 0, stream>>>(flags);

  // phase 1: |P| = |xs @ W_ih^T| -> sliced layout; signs -> plane (lossless)
  gemm_bt<false, false><<<(TT * BB / 128) * (NH / 128), 256, 0, stream>>>(
      (const void*)xs, Wih, (void*)hseq, plane, TT * BB, NH, NIN);

  // phase 2: recurrence (flag hint + tag-validated data; no producer drain)
  rnn_recur<<<256, 512, 0, stream>>>(hseq, plane, Whh, flags);

  // phase 3: out[b][t][o] = h_seq @ W_out^T (strips tags)
  gemm_bt<true, true><<<(TT * BB / 128) * (NOUT / 128), 256, 0, stream>>>(
      (const void*)hseq, Wout, d_out, plane, TT * BB, NOUT, NH);
}